// Round 14
// baseline (80.016 us; speedup 1.0000x reference)
//
#include <hip/hip_runtime.h>

// DCN-v2 low-rank mixture, L=3 E=4 D=512 R=64 B=16384.
// gate = softmax over size-1 axis == 1  -> G unused.
// xl' = x0 * (sum_e U_e tanh(C_e tanh(V_e^T xl)) + 4*bias) + xl, rows independent.
// R14: LDS-bound fix. All GEMMs on mfma_f32_32x32x16_f16 (2x MACs per 16B
//      fragment -> halves LDS b128 reads and weight-load instructions).
//      GEMM1: 2 row-tiles x 8 col-tiles (1 tile/wave). GEMM2: 1 tile/wave.
//      GEMM3: wave owns 32 d-cols, both row-tiles (acc 32, B read once).
//      Swizzle upgraded to (row&15)<<4 (16 slots -> ~2-way, free).
//      ROWS=64, 1024 thr, grid 256, LDS 160 KiB. Design-to-64-VGPR.

#define NL 3
#define NE 4
#define DD 512
#define RR 64
#define ROWS 64    // rows per block; grid = 16384/64 = 256 blocks
#define THREADS 1024

typedef __attribute__((ext_vector_type(8))) _Float16 f16x8;    // 8 fp16 = 4 VGPR
typedef __attribute__((ext_vector_type(16))) float f32x16;     // 32x32 accumulator

#define MFMA32(a, b, c) __builtin_amdgcn_mfma_f32_32x32x16_f16((a), (b), (c), 0, 0, 0)

__device__ __forceinline__ short f16b(float f) {
    _Float16 h = (_Float16)f;
    return __builtin_bit_cast(short, h);
}
__device__ __forceinline__ float f16tof(short s) {
    return (float)__builtin_bit_cast(_Float16, s);
}

__device__ __forceinline__ float ftanh(float x) {
    float t = __builtin_amdgcn_exp2f(x * 2.8853900817779268f);
    return 1.0f - 2.0f * __builtin_amdgcn_rcpf(t + 1.0f);
}

// ---- prep: fp16-cast + permute weights for 32x32x16 B-fragments ----
// Fragment element (lane ln, j): col = 32*cb + (ln&31), k = 16*kb + (ln>>5)*8 + j.
// Vb3[l][cb(8)][kb(32)][ln(64)][j(8)]   : v-col c=32cb+(ln&31) -> e=c>>6, r=c&63; k=d
// Ub3[l][cb(16)][kb(16)][ln][j]         : d-col = 32cb+(ln&31); k=(e,s) concat
// Ct3[l][e(4)][ct(2)][kb(4)][ln][j]     : s_out = 32ct+(ln&31); k=r
__global__ void prep_kernel(const float* __restrict__ U, const float* __restrict__ V,
                            const float* __restrict__ C,
                            short* __restrict__ Vb3, short* __restrict__ Ub3,
                            short* __restrict__ Ct3)
{
    int tid  = blockIdx.x * 256 + threadIdx.x;
    int nthr = gridDim.x * 256;
    for (int i = tid; i < NL * 131072; i += nthr) {
        int l = i >> 17; int q = i & 131071;
        int cb = q >> 14; int rem = q & 16383;
        int kb = rem >> 9; int ln = (rem >> 3) & 63; int j = rem & 7;
        int c = cb * 32 + (ln & 31);
        int e = c >> 6, r = c & 63;
        int d = kb * 16 + (ln >> 5) * 8 + j;
        Vb3[i] = f16b(V[(((size_t)l * NE + e) * DD + d) * RR + r]);
    }
    for (int i = tid; i < NL * 131072; i += nthr) {
        int l = i >> 17; int q = i & 131071;
        int cb = q >> 13; int rem = q & 8191;
        int kb = rem >> 9; int ln = (rem >> 3) & 63; int j = rem & 7;
        int dcol = cb * 32 + (ln & 31);
        int kidx = kb * 16 + (ln >> 5) * 8 + j;
        int e = kidx >> 6, s = kidx & 63;
        Ub3[i] = f16b(U[(((size_t)l * NE + e) * DD + dcol) * RR + s]);
    }
    for (int i = tid; i < NL * 16384; i += nthr) {
        int l = i >> 14; int q = i & 16383;
        int e = q >> 12; int rem = q & 4095;
        int ct = rem >> 11; int kb = (rem >> 9) & 3;
        int ln = (rem >> 3) & 63; int j = rem & 7;
        int s_out = ct * 32 + (ln & 31);
        int r = kb * 16 + (ln >> 5) * 8 + j;
        Ct3[i] = f16b(C[(((size_t)l * NE + e) * RR + r) * RR + s_out]);
    }
}

// 16-slot XOR swizzle: fragment reads span 32 rows -> (row&15)<<4 gives ~2-way (free)
#define XLB_ADDR(row, colbyte) (((row) * (DD * 2)) + ((colbyte) ^ (((row) & 15) << 4)))
#define VB_ADDR(row, colbyte)  (((row) * (NE * RR * 2)) + ((colbyte) ^ (((row) & 15) << 4)))

__global__ __launch_bounds__(THREADS, 4) void dcn_main(
    const float* __restrict__ x,
    const float* __restrict__ bias,
    const short* __restrict__ Vb3,
    const short* __restrict__ Ub3,
    const short* __restrict__ Ct3,
    float* __restrict__ out)
{
    __shared__ char xl_b[ROWS * DD * 2];        // 64 KiB fp16 xl carry tile (swizzled)
    __shared__ char x0_b[ROWS * DD * 2];        // 64 KiB fp16 x0 tile (swizzled)
    __shared__ char sbuf[ROWS * NE * RR * 2];   // 32 KiB shared v/cv tile (swizzled)

    const int t   = threadIdx.x;
    const int w   = t >> 6;          // wave 0..15
    const int ln  = t & 63;
    const int l31 = ln & 31;
    const int kh  = ln >> 5;         // k-half 0/1
    const int row_base = blockIdx.x * ROWS;

    // ---- preamble: x (fp32, coalesced float4) -> fp16 xl_b AND x0_b ----
    #pragma unroll
    for (int q = 0; q < 8; ++q) {
        int p   = t + q * THREADS;
        int row = p >> 7;                 // 128 float4 per row
        int d4  = (p & 127) << 2;
        const float4 v4 = *(const float4*)(x + (size_t)(row_base + row) * DD + d4);
        short4 pk;
        pk.x = f16b(v4.x); pk.y = f16b(v4.y); pk.z = f16b(v4.z); pk.w = f16b(v4.w);
        *(short4*)(xl_b + XLB_ADDR(row, d4 * 2)) = pk;
        *(short4*)(x0_b + XLB_ADDR(row, d4 * 2)) = pk;
    }
    __syncthreads();

    const int rt1 = w >> 3;          // GEMM1 row-tile
    const int cb1 = w & 7;           // GEMM1 col-tile (32 v-cols)
    const int e2  = w >> 2;          // GEMM2 expert
    const int rt2 = (w >> 1) & 1;    // GEMM2 row-tile
    const int ct2 = w & 1;           // GEMM2 col-tile

    #pragma unroll
    for (int layer = 0; layer < NL; ++layer) {
        const short* Vl = Vb3 + layer * 131072;
        const short* Ul = Ub3 + layer * 131072;
        const short* Cl = Ct3 + layer * 16384;
        const float* bl = bias + layer * DD;

        // ---- GEMM1: v = tanh(xl @ V); one 32x32 tile per wave ----
        f32x16 acc1 = {};
        #pragma unroll 4
        for (int kb = 0; kb < 32; ++kb) {
            f16x8 b = *(const f16x8*)(Vl + ((cb1 * 32 + kb) << 9) + ln * 8);
            f16x8 a = *(const f16x8*)(xl_b + XLB_ADDR(rt1 * 32 + l31, kb * 32 + kh * 16));
            acc1 = MFMA32(a, b, acc1);
        }
        #pragma unroll
        for (int reg = 0; reg < 16; ++reg) {
            int row = rt1 * 32 + kh * 4 + (reg & 3) + 8 * (reg >> 2);
            int col = cb1 * 32 + l31;
            *(short*)(sbuf + VB_ADDR(row, col * 2)) = f16b(ftanh(acc1[reg]));
        }
        __syncthreads();   // v visible

        // ---- GEMM2: cv = tanh(v @ C_e); one 32x32 tile per wave ----
        f32x16 acc2 = {};
        #pragma unroll
        for (int kb = 0; kb < 4; ++kb) {
            f16x8 b = *(const f16x8*)(Cl + (((e2 * 2 + ct2) * 4 + kb) << 9) + ln * 8);
            f16x8 a = *(const f16x8*)(sbuf + VB_ADDR(rt2 * 32 + l31,
                                                     e2 * 128 + kb * 32 + kh * 16));
            acc2 = MFMA32(a, b, acc2);
        }
        float cvv[16];
        #pragma unroll
        for (int reg = 0; reg < 16; ++reg) cvv[reg] = ftanh(acc2[reg]);
        __syncthreads();   // all v-reads done before cv overwrites sbuf
        #pragma unroll
        for (int reg = 0; reg < 16; ++reg) {
            int row = rt2 * 32 + kh * 4 + (reg & 3) + 8 * (reg >> 2);
            int col = e2 * 64 + ct2 * 32 + l31;
            *(short*)(sbuf + VB_ADDR(row, col * 2)) = f16b(cvv[reg]);
        }
        __syncthreads();   // cv visible

        // ---- GEMM3: ucv = cv @ W; wave owns 32 d-cols, BOTH row-tiles (B read once) ----
        f32x16 accA = {};   // row-tile 0
        f32x16 accB = {};   // row-tile 1
        #pragma unroll 2
        for (int kb = 0; kb < 16; ++kb) {
            f16x8 b  = *(const f16x8*)(Ul + ((w * 16 + kb) << 9) + ln * 8);
            f16x8 a0 = *(const f16x8*)(sbuf + VB_ADDR(l31,      kb * 32 + kh * 16));
            f16x8 a1 = *(const f16x8*)(sbuf + VB_ADDR(32 + l31, kb * 32 + kh * 16));
            accA = MFMA32(a0, b, accA);
            accB = MFMA32(a1, b, accB);
        }

        // ---- epilogue (pure LDS): xl' = x0*(ucv + 4*bias) + xl_old ----
        const int col = w * 32 + l31;
        const float bv = 4.0f * bl[col];
        #pragma unroll
        for (int reg = 0; reg < 16; ++reg) {
            int row = kh * 4 + (reg & 3) + 8 * (reg >> 2);
            float xo = f16tof(*(const short*)(xl_b + XLB_ADDR(row, col * 2)));
            float x0 = f16tof(*(const short*)(x0_b + XLB_ADDR(row, col * 2)));
            *(short*)(xl_b + XLB_ADDR(row, col * 2)) = f16b(x0 * (accA[reg] + bv) + xo);
        }
        #pragma unroll
        for (int reg = 0; reg < 16; ++reg) {
            int row = 32 + kh * 4 + (reg & 3) + 8 * (reg >> 2);
            float xo = f16tof(*(const short*)(xl_b + XLB_ADDR(row, col * 2)));
            float x0 = f16tof(*(const short*)(x0_b + XLB_ADDR(row, col * 2)));
            *(short*)(xl_b + XLB_ADDR(row, col * 2)) = f16b(x0 * (accB[reg] + bv) + xo);
        }
        __syncthreads();   // xl' visible to next GEMM1 / final copy
    }

    // ---- final: coalesced float4 store of xl_b (fp16 -> fp32) ----
    #pragma unroll
    for (int q = 0; q < 8; ++q) {
        int p   = t + q * THREADS;
        int row = p >> 7;
        int d4  = (p & 127) << 2;
        short4 pk = *(const short4*)(xl_b + XLB_ADDR(row, d4 * 2));
        float4 v4;
        v4.x = f16tof(pk.x); v4.y = f16tof(pk.y); v4.z = f16tof(pk.z); v4.w = f16tof(pk.w);
        *(float4*)(out + (size_t)(row_base + row) * DD + d4) = v4;
    }
}

extern "C" void kernel_launch(void* const* d_in, const int* in_sizes, int n_in,
                              void* d_out, int out_size, void* d_ws, size_t ws_size,
                              hipStream_t stream) {
    const float* x    = (const float*)d_in[0];
    const float* U    = (const float*)d_in[1];
    const float* V    = (const float*)d_in[2];
    const float* C    = (const float*)d_in[3];
    // d_in[4] = G : unused (gate == 1 exactly)
    const float* bias = (const float*)d_in[5];
    float* out = (float*)d_out;

    short* Vb3 = (short*)d_ws;                 // 786432 B
    short* Ub3 = Vb3 + NL * 131072;            // 786432 B
    short* Ct3 = Ub3 + NL * 131072;            // 98304 B  (total ~1.6 MiB)

    prep_kernel<<<dim3(256), dim3(256), 0, stream>>>(U, V, C, Vb3, Ub3, Ct3);
    dcn_main<<<dim3(16384 / ROWS), dim3(THREADS), 0, stream>>>(x, bias, Vb3, Ub3, Ct3, out);
}